// Round 6
// baseline (170.218 us; speedup 1.0000x reference)
//
#include <hip/hip_runtime.h>

#define NV 128
typedef unsigned int uint32;

#define TBL_ENTRIES ((size_t)NV * NV * NV)           // 2M entries x 64 B = 128 MiB
#define TBL_BYTES   (TBL_ENTRIES * 64)
// The x=127 plane of the table (last 1 MiB) is NEVER read by the main kernel
// (x0,y0,z0 <= 126) and never written as entries by repack. Scratch there:
//   Sc = ws + TBL_BYTES - 32768 : 4064 per-repack-block scales (16 KB)

#define ROWSTRIDE 257   // float4 units per staged row (+1 pad vs 256)

// ---------------------------------------------------------------------------
// LDS-tiled full-replication repack with LOCAL per-block scale.
// Block = (x, y-band of 4), x in [0,126]. Stages rows (x..x+1, y0..y0+4)
// = 10 rows x 4 KB into LDS (coalesced), computing the band's absmax on the
// fly; quantizes with 127/local_max; writes its scale to Sc[blockIdx.x].
// Entry(x,y,z) = 4 uint4 words w=(xr*2+yr):
//   word = { pack(z p0-3), pack(z p4-7), pack(z1 p0-3), pack(z1 p4-7) }
//   for corner row (x+xr, y+yr).
// ---------------------------------------------------------------------------
__device__ __forceinline__ uint32 pack4(float4 v, float inv) {
    uint32 a = (uint32)__float2int_rn(v.x * inv) & 255u;
    uint32 b = (uint32)__float2int_rn(v.y * inv) & 255u;
    uint32 c = (uint32)__float2int_rn(v.z * inv) & 255u;
    uint32 d = (uint32)__float2int_rn(v.w * inv) & 255u;
    return a | (b << 8) | (c << 16) | (d << 24);
}

__global__ __launch_bounds__(256) void repack_full_kernel(
        const float* __restrict__ grid, float* __restrict__ Sc,
        uint4* __restrict__ tbl) {
    __shared__ float4 lds4[10 * ROWSTRIDE];          // ~41 KB
    __shared__ float wm[4];
    int tid = threadIdx.x;
    int x  = blockIdx.x >> 5;                        // 0..126
    int y0 = (blockIdx.x & 31) << 2;                 // 0,4,...,124

    // Stage 10 grid rows (r = xi*5 + yj), tracking local absmax
    const float4* g4 = reinterpret_cast<const float4*>(grid);
    float mm = 0.0f;
    for (int i = tid; i < 10 * 256; i += 256) {
        int r = i >> 8, c = i & 255;
        int xi = r / 5, yj = r - xi * 5;
        int gx_ = min(x + xi, NV - 1);
        int gy_ = min(y0 + yj, NV - 1);
        float4 v = g4[(size_t)(gx_ * NV + gy_) * 256 + c];
        lds4[r * ROWSTRIDE + c] = v;
        mm = fmaxf(mm, fmaxf(fmaxf(fabsf(v.x), fabsf(v.y)),
                             fmaxf(fabsf(v.z), fabsf(v.w))));
    }

    // Block-reduce local absmax
    for (int off = 32; off > 0; off >>= 1)
        mm = fmaxf(mm, __shfl_down(mm, off));
    int lane = tid & 63, wv = tid >> 6;
    if (lane == 0) wm[wv] = mm;
    __syncthreads();                                 // covers lds4 + wm
    float amax = fmaxf(fmaxf(fmaxf(wm[0], wm[1]), fmaxf(wm[2], wm[3])), 1e-30f);
    if (tid == 0) Sc[blockIdx.x] = amax;
    float inv = 127.0f / amax;

    // Emit: 4 y * 128 z * 4 words = 2048 uint4 words, coalesced
    for (int i = tid; i < 2048; i += 256) {
        int L = i >> 2, w = i & 3;                   // entry-in-band, word
        int z = L & 127, yy = L >> 7;                // yy in 0..3
        int xr = w >> 1, yr = w & 1;
        int row = xr * 5 + yy + yr;
        int z1 = min(z + 1, NV - 1);
        float4 a0 = lds4[row * ROWSTRIDE + z * 2];
        float4 a1 = lds4[row * ROWSTRIDE + z * 2 + 1];
        float4 b0 = lds4[row * ROWSTRIDE + z1 * 2];
        float4 b1 = lds4[row * ROWSTRIDE + z1 * 2 + 1];
        uint4 word;
        word.x = pack4(a0, inv);
        word.y = pack4(a1, inv);
        word.z = pack4(b0, inv);
        word.w = pack4(b1, inv);
        size_t e = (size_t)((x * NV) + y0 + yy) * NV + z;
        tbl[e * 4 + w] = word;
    }
}

// ---------------------------------------------------------------------------
// Main gather: 2 queries/thread, one 64-B aligned entry per query, scale
// looked up from the 16 KB L2-resident Sc array.
// ---------------------------------------------------------------------------
__device__ __forceinline__ float4 dec4(uint32 w) {
    return make_float4((float)((int)(w << 24) >> 24),
                       (float)((int)(w << 16) >> 24),
                       (float)((int)(w <<  8) >> 24),
                       (float)((int)  w       >> 24));
}

__device__ __forceinline__ void acc4(float4& a, float4 v, float w) {
    a.x = fmaf(v.x, w, a.x);
    a.y = fmaf(v.y, w, a.y);
    a.z = fmaf(v.z, w, a.z);
    a.w = fmaf(v.w, w, a.w);
}

__device__ __forceinline__ void cell_of(const float* pf, int slot, size_t& e,
                                        int& sidx, float& fx, float& fy, float& fz) {
    float px = pf[slot * 3 + 0];
    float py = pf[slot * 3 + 1];
    float pz = pf[slot * 3 + 2];
    px = fminf(fmaxf(px, 0.0f), 1.0f) * (float)(NV - 1);
    py = fminf(fmaxf(py, 0.0f), 1.0f) * (float)(NV - 1);
    pz = fminf(fmaxf(pz, 0.0f), 1.0f) * (float)(NV - 1);
    int x0 = min((int)px, NV - 2);
    int y0 = min((int)py, NV - 2);
    int z0 = min((int)pz, NV - 2);
    fx = px - (float)x0;
    fy = py - (float)y0;
    fz = pz - (float)z0;
    e = (size_t)((x0 * NV + y0) * NV + z0) * 4;
    sidx = (x0 << 5) | (y0 >> 2);
}

__device__ __forceinline__ void lerp_store(const uint4* E, float fx, float fy,
                                           float fz, float s, float4* o4, int q) {
    float gx = 1.0f - fx, gy = 1.0f - fy, gz = 1.0f - fz;
    float w0 = gx * gy, w1 = gx * fy, w2 = fx * gy, w3 = fx * fy;
    float4 a03 = make_float4(0.f, 0.f, 0.f, 0.f);
    float4 a47 = make_float4(0.f, 0.f, 0.f, 0.f);
    {
        float wg = w0 * gz, wf = w0 * fz;
        acc4(a03, dec4(E[0].x), wg); acc4(a47, dec4(E[0].y), wg);
        acc4(a03, dec4(E[0].z), wf); acc4(a47, dec4(E[0].w), wf);
    }
    {
        float wg = w1 * gz, wf = w1 * fz;
        acc4(a03, dec4(E[1].x), wg); acc4(a47, dec4(E[1].y), wg);
        acc4(a03, dec4(E[1].z), wf); acc4(a47, dec4(E[1].w), wf);
    }
    {
        float wg = w2 * gz, wf = w2 * fz;
        acc4(a03, dec4(E[2].x), wg); acc4(a47, dec4(E[2].y), wg);
        acc4(a03, dec4(E[2].z), wf); acc4(a47, dec4(E[2].w), wf);
    }
    {
        float wg = w3 * gz, wf = w3 * fz;
        acc4(a03, dec4(E[3].x), wg); acc4(a47, dec4(E[3].y), wg);
        acc4(a03, dec4(E[3].z), wf); acc4(a47, dec4(E[3].w), wf);
    }
    o4[q * 2 + 0] = make_float4(a03.x * s, a03.y * s, a03.z * s, a03.w * s);
    o4[q * 2 + 1] = make_float4(a47.x * s, a47.y * s, a47.z * s, a47.w * s);
}

__global__ __launch_bounds__(256) void trilerp_full_kernel(
        const float* __restrict__ ipos, const uint4* __restrict__ tbl,
        const float* __restrict__ Sc, float* __restrict__ out, int nq) {
    __shared__ float4 pls[384];                      // 512 queries x 12 B
    int tid = threadIdx.x;
    int blk = blockIdx.x;
    const float4* ip4 = reinterpret_cast<const float4*>(ipos);
    int n4p = (int)(((long long)nq * 3) >> 2);
    int sbase = blk * 384;
    #pragma unroll
    for (int k = 0; k < 2; ++k) {
        int i = tid + k * 256;
        if (i < 384 && sbase + i < n4p) pls[i] = ip4[sbase + i];
    }
    __syncthreads();

    int q0 = blk * 512 + tid;
    int q1 = q0 + 256;
    const float* pf = reinterpret_cast<const float*>(pls);
    float4* o4 = reinterpret_cast<float4*>(out);

    size_t e0 = 0, e1 = 0;
    int si0 = 0, si1 = 0;
    float fx0, fy0, fz0, fx1, fy1, fz1;
    bool v0 = q0 < nq, v1 = q1 < nq;
    if (v0) cell_of(pf, tid,       e0, si0, fx0, fy0, fz0);
    if (v1) cell_of(pf, tid + 256, e1, si1, fx1, fy1, fz1);

    uint4 E0[4], E1[4];
    float s0 = 0.f, s1 = 0.f;
    if (v0) {
        E0[0] = tbl[e0]; E0[1] = tbl[e0+1]; E0[2] = tbl[e0+2]; E0[3] = tbl[e0+3];
        s0 = Sc[si0] * (1.0f / 127.0f);
    }
    if (v1) {
        E1[0] = tbl[e1]; E1[1] = tbl[e1+1]; E1[2] = tbl[e1+2]; E1[3] = tbl[e1+3];
        s1 = Sc[si1] * (1.0f / 127.0f);
    }

    if (v0) lerp_store(E0, fx0, fy0, fz0, s0, o4, q0);
    if (v1) lerp_store(E1, fx1, fy1, fz1, s1, o4, q1);
}

// ---------------------------------------------------------------------------
// Fallback (direct fp32 gather) if workspace can't hold the table.
// ---------------------------------------------------------------------------
__device__ __forceinline__ float4 lerp4(float4 a, float4 b, float t) {
    return make_float4(fmaf(t, b.x - a.x, a.x),
                       fmaf(t, b.y - a.y, a.y),
                       fmaf(t, b.z - a.z, a.z),
                       fmaf(t, b.w - a.w, a.w));
}

__global__ __launch_bounds__(256) void voxel_trilerp_kernel(
        const float* __restrict__ ipos,
        const float* __restrict__ grid,
        float* __restrict__ out,
        int nq) {
    const int tid = blockIdx.x * blockDim.x + threadIdx.x;
    const int stride = gridDim.x * blockDim.x;
    const float4* __restrict__ g4 = reinterpret_cast<const float4*>(grid);
    float4* __restrict__ o4 = reinterpret_cast<float4*>(out);

    const int Z4 = 2;
    const int Y4 = NV * 8 / 4;
    const int X4 = NV * NV * 8 / 4;

    for (int q = tid; q < nq; q += stride) {
        float px = ipos[q * 3 + 0];
        float py = ipos[q * 3 + 1];
        float pz = ipos[q * 3 + 2];

        px = fminf(fmaxf(px, 0.0f), 1.0f) * (float)(NV - 1);
        py = fminf(fmaxf(py, 0.0f), 1.0f) * (float)(NV - 1);
        pz = fminf(fmaxf(pz, 0.0f), 1.0f) * (float)(NV - 1);

        int x0 = min((int)px, NV - 2);
        int y0 = min((int)py, NV - 2);
        int z0 = min((int)pz, NV - 2);

        float fx = px - (float)x0;
        float fy = py - (float)y0;
        float fz = pz - (float)z0;

        int b = x0 * X4 + y0 * Y4 + z0 * Z4;

        float4 c00a0 = g4[b],                c00a1 = g4[b + 1];
        float4 c00b0 = g4[b + Z4],           c00b1 = g4[b + Z4 + 1];
        float4 c01a0 = g4[b + Y4],           c01a1 = g4[b + Y4 + 1];
        float4 c01b0 = g4[b + Y4 + Z4],      c01b1 = g4[b + Y4 + Z4 + 1];
        float4 c10a0 = g4[b + X4],           c10a1 = g4[b + X4 + 1];
        float4 c10b0 = g4[b + X4 + Z4],      c10b1 = g4[b + X4 + Z4 + 1];
        float4 c11a0 = g4[b + X4 + Y4],      c11a1 = g4[b + X4 + Y4 + 1];
        float4 c11b0 = g4[b + X4 + Y4 + Z4], c11b1 = g4[b + X4 + Y4 + Z4 + 1];

        float4 z00_0 = lerp4(c00a0, c00b0, fz), z00_1 = lerp4(c00a1, c00b1, fz);
        float4 z01_0 = lerp4(c01a0, c01b0, fz), z01_1 = lerp4(c01a1, c01b1, fz);
        float4 z10_0 = lerp4(c10a0, c10b0, fz), z10_1 = lerp4(c10a1, c10b1, fz);
        float4 z11_0 = lerp4(c11a0, c11b0, fz), z11_1 = lerp4(c11a1, c11b1, fz);

        float4 y0_0 = lerp4(z00_0, z01_0, fy), y0_1 = lerp4(z00_1, z01_1, fy);
        float4 y1_0 = lerp4(z10_0, z11_0, fy), y1_1 = lerp4(z10_1, z11_1, fy);

        float4 r0 = lerp4(y0_0, y1_0, fx);
        float4 r1 = lerp4(y0_1, y1_1, fx);

        o4[q * 2 + 0] = r0;
        o4[q * 2 + 1] = r1;
    }
}

extern "C" void kernel_launch(void* const* d_in, const int* in_sizes, int n_in,
                              void* d_out, int out_size, void* d_ws, size_t ws_size,
                              hipStream_t stream) {
    const float* ipos = (const float*)d_in[0];
    const float* grid = (const float*)d_in[1];
    float* out = (float*)d_out;

    const int nq = in_sizes[0] / 3;           // 4194304

    if (ws_size >= TBL_BYTES) {
        uint4* tbl = (uint4*)d_ws;
        float* Sc = (float*)((char*)d_ws + TBL_BYTES - 32768);  // 4064 scales

        repack_full_kernel<<<127 * 32, 256, 0, stream>>>(grid, Sc, tbl);
        trilerp_full_kernel<<<(nq + 511) / 512, 256, 0, stream>>>(
            ipos, tbl, Sc, out, nq);
    } else {
        voxel_trilerp_kernel<<<2048, 256, 0, stream>>>(ipos, grid, out, nq);
    }
}

// Round 7
// 170.180 us; speedup vs baseline: 1.0002x; 1.0002x over previous
//
#include <hip/hip_runtime.h>
#include <hip/hip_fp16.h>

#define NV 128
typedef unsigned int uint32;

#define TBL_ENTRIES ((size_t)NV * NV * NV)           // 2M entries x 64 B = 128 MiB
#define TBL_BYTES   (TBL_ENTRIES * 64)
// The x=127 plane of the table (last 1 MiB) is NEVER read by the main kernel
// (x0,y0,z0 <= 126) and never written as entries by repack. Scratch there:
//   Sc = ws + TBL_BYTES - 32768 : 4064 per-repack-block scales, fp16 (8 KB)

#define ROWSTRIDE 257   // float4 units per staged row (+1 pad vs 256)

// ---------------------------------------------------------------------------
// LDS-tiled full-replication repack with LOCAL per-block scale (fp16).
// Block = (x, y-band of 4), x in [0,126]. Quantizes with the fp16-ROUNDED
// scale so main-kernel reconstruction is exact w.r.t. the stored scale.
// ---------------------------------------------------------------------------
__device__ __forceinline__ uint32 pack4(float4 v, float inv) {
    int a = max(-127, min(127, __float2int_rn(v.x * inv)));
    int b = max(-127, min(127, __float2int_rn(v.y * inv)));
    int c = max(-127, min(127, __float2int_rn(v.z * inv)));
    int d = max(-127, min(127, __float2int_rn(v.w * inv)));
    return ((uint32)a & 255u) | (((uint32)b & 255u) << 8) |
           (((uint32)c & 255u) << 16) | (((uint32)d & 255u) << 24);
}

__global__ __launch_bounds__(256) void repack_full_kernel(
        const float* __restrict__ grid, __half* __restrict__ Sc,
        uint4* __restrict__ tbl) {
    __shared__ float4 lds4[10 * ROWSTRIDE];          // ~41 KB
    __shared__ float wm[4];
    int tid = threadIdx.x;
    int x  = blockIdx.x >> 5;                        // 0..126
    int y0 = (blockIdx.x & 31) << 2;                 // 0,4,...,124

    // Stage 10 grid rows (r = xi*5 + yj), tracking local absmax
    const float4* g4 = reinterpret_cast<const float4*>(grid);
    float mm = 0.0f;
    for (int i = tid; i < 10 * 256; i += 256) {
        int r = i >> 8, c = i & 255;
        int xi = r / 5, yj = r - xi * 5;
        int gx_ = min(x + xi, NV - 1);
        int gy_ = min(y0 + yj, NV - 1);
        float4 v = g4[(size_t)(gx_ * NV + gy_) * 256 + c];
        lds4[r * ROWSTRIDE + c] = v;
        mm = fmaxf(mm, fmaxf(fmaxf(fabsf(v.x), fabsf(v.y)),
                             fmaxf(fabsf(v.z), fabsf(v.w))));
    }

    // Block-reduce local absmax
    for (int off = 32; off > 0; off >>= 1)
        mm = fmaxf(mm, __shfl_down(mm, off));
    int lane = tid & 63, wv = tid >> 6;
    if (lane == 0) wm[wv] = mm;
    __syncthreads();                                 // covers lds4 + wm
    float amax = fmaxf(fmaxf(fmaxf(wm[0], wm[1]), fmaxf(wm[2], wm[3])), 1e-30f);
    __half hs = __float2half_rn(amax);
    float amax_r = __half2float(hs);                 // quantize w/ rounded scale
    if (tid == 0) Sc[blockIdx.x] = hs;
    float inv = 127.0f / amax_r;

    // Emit: 4 y * 128 z * 4 words = 2048 uint4 words, coalesced
    for (int i = tid; i < 2048; i += 256) {
        int L = i >> 2, w = i & 3;                   // entry-in-band, word
        int z = L & 127, yy = L >> 7;                // yy in 0..3
        int xr = w >> 1, yr = w & 1;
        int row = xr * 5 + yy + yr;
        int z1 = min(z + 1, NV - 1);
        float4 a0 = lds4[row * ROWSTRIDE + z * 2];
        float4 a1 = lds4[row * ROWSTRIDE + z * 2 + 1];
        float4 b0 = lds4[row * ROWSTRIDE + z1 * 2];
        float4 b1 = lds4[row * ROWSTRIDE + z1 * 2 + 1];
        uint4 word;
        word.x = pack4(a0, inv);
        word.y = pack4(a1, inv);
        word.z = pack4(b0, inv);
        word.w = pack4(b1, inv);
        size_t e = (size_t)((x * NV) + y0 + yy) * NV + z;
        tbl[e * 4 + w] = word;
    }
}

// ---------------------------------------------------------------------------
// Main gather: 2 queries/thread, one 64-B aligned entry per query.
// Scales staged into LDS (8 KB) -> per-query scale is a ds_read, keeping the
// vector-memory path exclusively for the entry gathers.
// ---------------------------------------------------------------------------
__device__ __forceinline__ float4 dec4(uint32 w) {
    return make_float4((float)((int)(w << 24) >> 24),
                       (float)((int)(w << 16) >> 24),
                       (float)((int)(w <<  8) >> 24),
                       (float)((int)  w       >> 24));
}

__device__ __forceinline__ void acc4(float4& a, float4 v, float w) {
    a.x = fmaf(v.x, w, a.x);
    a.y = fmaf(v.y, w, a.y);
    a.z = fmaf(v.z, w, a.z);
    a.w = fmaf(v.w, w, a.w);
}

__device__ __forceinline__ void cell_of(const float* pf, int slot, size_t& e,
                                        int& sidx, float& fx, float& fy, float& fz) {
    float px = pf[slot * 3 + 0];
    float py = pf[slot * 3 + 1];
    float pz = pf[slot * 3 + 2];
    px = fminf(fmaxf(px, 0.0f), 1.0f) * (float)(NV - 1);
    py = fminf(fmaxf(py, 0.0f), 1.0f) * (float)(NV - 1);
    pz = fminf(fmaxf(pz, 0.0f), 1.0f) * (float)(NV - 1);
    int x0 = min((int)px, NV - 2);
    int y0 = min((int)py, NV - 2);
    int z0 = min((int)pz, NV - 2);
    fx = px - (float)x0;
    fy = py - (float)y0;
    fz = pz - (float)z0;
    e = (size_t)((x0 * NV + y0) * NV + z0) * 4;
    sidx = (x0 << 5) | (y0 >> 2);
}

__device__ __forceinline__ void lerp_store(const uint4* E, float fx, float fy,
                                           float fz, float s, float4* o4, int q) {
    float gx = 1.0f - fx, gy = 1.0f - fy, gz = 1.0f - fz;
    float w0 = gx * gy, w1 = gx * fy, w2 = fx * gy, w3 = fx * fy;
    float4 a03 = make_float4(0.f, 0.f, 0.f, 0.f);
    float4 a47 = make_float4(0.f, 0.f, 0.f, 0.f);
    {
        float wg = w0 * gz, wf = w0 * fz;
        acc4(a03, dec4(E[0].x), wg); acc4(a47, dec4(E[0].y), wg);
        acc4(a03, dec4(E[0].z), wf); acc4(a47, dec4(E[0].w), wf);
    }
    {
        float wg = w1 * gz, wf = w1 * fz;
        acc4(a03, dec4(E[1].x), wg); acc4(a47, dec4(E[1].y), wg);
        acc4(a03, dec4(E[1].z), wf); acc4(a47, dec4(E[1].w), wf);
    }
    {
        float wg = w2 * gz, wf = w2 * fz;
        acc4(a03, dec4(E[2].x), wg); acc4(a47, dec4(E[2].y), wg);
        acc4(a03, dec4(E[2].z), wf); acc4(a47, dec4(E[2].w), wf);
    }
    {
        float wg = w3 * gz, wf = w3 * fz;
        acc4(a03, dec4(E[3].x), wg); acc4(a47, dec4(E[3].y), wg);
        acc4(a03, dec4(E[3].z), wf); acc4(a47, dec4(E[3].w), wf);
    }
    o4[q * 2 + 0] = make_float4(a03.x * s, a03.y * s, a03.z * s, a03.w * s);
    o4[q * 2 + 1] = make_float4(a47.x * s, a47.y * s, a47.z * s, a47.w * s);
}

__global__ __launch_bounds__(256) void trilerp_full_kernel(
        const float* __restrict__ ipos, const uint4* __restrict__ tbl,
        const __half* __restrict__ Sc, float* __restrict__ out, int nq) {
    __shared__ float4 pls[384];                      // 512 queries x 12 B
    __shared__ __half scl[4096];                     // 8 KB scale cache
    int tid = threadIdx.x;
    int blk = blockIdx.x;

    // Stage scales: 4096 halves = 512 uint4, 2 coalesced iterations
    {
        const uint4* sc4 = reinterpret_cast<const uint4*>(Sc);
        uint4* sl4 = reinterpret_cast<uint4*>(scl);
        sl4[tid] = sc4[tid];
        sl4[tid + 256] = sc4[tid + 256];
    }
    // Stage positions
    const float4* ip4 = reinterpret_cast<const float4*>(ipos);
    int n4p = (int)(((long long)nq * 3) >> 2);
    int sbase = blk * 384;
    #pragma unroll
    for (int k = 0; k < 2; ++k) {
        int i = tid + k * 256;
        if (i < 384 && sbase + i < n4p) pls[i] = ip4[sbase + i];
    }
    __syncthreads();

    int q0 = blk * 512 + tid;
    int q1 = q0 + 256;
    const float* pf = reinterpret_cast<const float*>(pls);
    float4* o4 = reinterpret_cast<float4*>(out);

    size_t e0 = 0, e1 = 0;
    int si0 = 0, si1 = 0;
    float fx0, fy0, fz0, fx1, fy1, fz1;
    bool v0 = q0 < nq, v1 = q1 < nq;
    if (v0) cell_of(pf, tid,       e0, si0, fx0, fy0, fz0);
    if (v1) cell_of(pf, tid + 256, e1, si1, fx1, fy1, fz1);

    uint4 E0[4], E1[4];
    float s0 = 0.f, s1 = 0.f;
    if (v0) {
        E0[0] = tbl[e0]; E0[1] = tbl[e0+1]; E0[2] = tbl[e0+2]; E0[3] = tbl[e0+3];
        s0 = __half2float(scl[si0]) * (1.0f / 127.0f);
    }
    if (v1) {
        E1[0] = tbl[e1]; E1[1] = tbl[e1+1]; E1[2] = tbl[e1+2]; E1[3] = tbl[e1+3];
        s1 = __half2float(scl[si1]) * (1.0f / 127.0f);
    }

    if (v0) lerp_store(E0, fx0, fy0, fz0, s0, o4, q0);
    if (v1) lerp_store(E1, fx1, fy1, fz1, s1, o4, q1);
}

// ---------------------------------------------------------------------------
// Fallback (direct fp32 gather) if workspace can't hold the table.
// ---------------------------------------------------------------------------
__device__ __forceinline__ float4 lerp4(float4 a, float4 b, float t) {
    return make_float4(fmaf(t, b.x - a.x, a.x),
                       fmaf(t, b.y - a.y, a.y),
                       fmaf(t, b.z - a.z, a.z),
                       fmaf(t, b.w - a.w, a.w));
}

__global__ __launch_bounds__(256) void voxel_trilerp_kernel(
        const float* __restrict__ ipos,
        const float* __restrict__ grid,
        float* __restrict__ out,
        int nq) {
    const int tid = blockIdx.x * blockDim.x + threadIdx.x;
    const int stride = gridDim.x * blockDim.x;
    const float4* __restrict__ g4 = reinterpret_cast<const float4*>(grid);
    float4* __restrict__ o4 = reinterpret_cast<float4*>(out);

    const int Z4 = 2;
    const int Y4 = NV * 8 / 4;
    const int X4 = NV * NV * 8 / 4;

    for (int q = tid; q < nq; q += stride) {
        float px = ipos[q * 3 + 0];
        float py = ipos[q * 3 + 1];
        float pz = ipos[q * 3 + 2];

        px = fminf(fmaxf(px, 0.0f), 1.0f) * (float)(NV - 1);
        py = fminf(fmaxf(py, 0.0f), 1.0f) * (float)(NV - 1);
        pz = fminf(fmaxf(pz, 0.0f), 1.0f) * (float)(NV - 1);

        int x0 = min((int)px, NV - 2);
        int y0 = min((int)py, NV - 2);
        int z0 = min((int)pz, NV - 2);

        float fx = px - (float)x0;
        float fy = py - (float)y0;
        float fz = pz - (float)z0;

        int b = x0 * X4 + y0 * Y4 + z0 * Z4;

        float4 c00a0 = g4[b],                c00a1 = g4[b + 1];
        float4 c00b0 = g4[b + Z4],           c00b1 = g4[b + Z4 + 1];
        float4 c01a0 = g4[b + Y4],           c01a1 = g4[b + Y4 + 1];
        float4 c01b0 = g4[b + Y4 + Z4],      c01b1 = g4[b + Y4 + Z4 + 1];
        float4 c10a0 = g4[b + X4],           c10a1 = g4[b + X4 + 1];
        float4 c10b0 = g4[b + X4 + Z4],      c10b1 = g4[b + X4 + Z4 + 1];
        float4 c11a0 = g4[b + X4 + Y4],      c11a1 = g4[b + X4 + Y4 + 1];
        float4 c11b0 = g4[b + X4 + Y4 + Z4], c11b1 = g4[b + X4 + Y4 + Z4 + 1];

        float4 z00_0 = lerp4(c00a0, c00b0, fz), z00_1 = lerp4(c00a1, c00b1, fz);
        float4 z01_0 = lerp4(c01a0, c01b0, fz), z01_1 = lerp4(c01a1, c01b1, fz);
        float4 z10_0 = lerp4(c10a0, c10b0, fz), z10_1 = lerp4(c10a1, c10b1, fz);
        float4 z11_0 = lerp4(c11a0, c11b0, fz), z11_1 = lerp4(c11a1, c11b1, fz);

        float4 y0_0 = lerp4(z00_0, z01_0, fy), y0_1 = lerp4(z00_1, z01_1, fy);
        float4 y1_0 = lerp4(z10_0, z11_0, fy), y1_1 = lerp4(z10_1, z11_1, fy);

        float4 r0 = lerp4(y0_0, y1_0, fx);
        float4 r1 = lerp4(y0_1, y1_1, fx);

        o4[q * 2 + 0] = r0;
        o4[q * 2 + 1] = r1;
    }
}

extern "C" void kernel_launch(void* const* d_in, const int* in_sizes, int n_in,
                              void* d_out, int out_size, void* d_ws, size_t ws_size,
                              hipStream_t stream) {
    const float* ipos = (const float*)d_in[0];
    const float* grid = (const float*)d_in[1];
    float* out = (float*)d_out;

    const int nq = in_sizes[0] / 3;           // 4194304

    if (ws_size >= TBL_BYTES) {
        uint4* tbl = (uint4*)d_ws;
        __half* Sc = (__half*)((char*)d_ws + TBL_BYTES - 32768);  // 4064 fp16 scales

        repack_full_kernel<<<127 * 32, 256, 0, stream>>>(grid, Sc, tbl);
        trilerp_full_kernel<<<(nq + 511) / 512, 256, 0, stream>>>(
            ipos, tbl, Sc, out, nq);
    } else {
        voxel_trilerp_kernel<<<2048, 256, 0, stream>>>(ipos, grid, out, nq);
    }
}

// Round 9
// 157.783 us; speedup vs baseline: 1.0788x; 1.0786x over previous
//
#include <hip/hip_runtime.h>
#include <hip/hip_fp16.h>

#define NV 128
typedef unsigned int uint32;
typedef float fx4 __attribute__((ext_vector_type(4)));   // NT-capable float4

#define TBL_ENTRIES ((size_t)NV * NV * NV)           // 2M entries x 64 B = 128 MiB
#define TBL_BYTES   (TBL_ENTRIES * 64)
// The x=127 plane of the table (last 1 MiB) is NEVER read by the main kernel
// (x0,y0,z0 <= 126) and never written as entries by repack. Scratch there:
//   Sc = ws + TBL_BYTES - 32768 : 4064 per-repack-block scales, fp16 (8 KB)

#define ROWSTRIDE 257   // float4 units per staged row (+1 pad vs 256)

// ---------------------------------------------------------------------------
// LDS-tiled full-replication repack with LOCAL per-block scale (fp16,
// rounded UP so |q| <= 127 holds without clamping).
// Block = (x, y-band of 4), x in [0,126].
// ---------------------------------------------------------------------------
__device__ __forceinline__ uint32 pack4(float4 v, float inv) {
    uint32 a = (uint32)__float2int_rn(v.x * inv) & 255u;
    uint32 b = (uint32)__float2int_rn(v.y * inv) & 255u;
    uint32 c = (uint32)__float2int_rn(v.z * inv) & 255u;
    uint32 d = (uint32)__float2int_rn(v.w * inv) & 255u;
    return a | (b << 8) | (c << 16) | (d << 24);
}

__global__ __launch_bounds__(256) void repack_full_kernel(
        const float* __restrict__ grid, __half* __restrict__ Sc,
        uint4* __restrict__ tbl) {
    __shared__ float4 lds4[10 * ROWSTRIDE];          // ~41 KB
    __shared__ float wm[4];
    int tid = threadIdx.x;
    int x  = blockIdx.x >> 5;                        // 0..126
    int y0 = (blockIdx.x & 31) << 2;                 // 0,4,...,124

    // Stage 10 grid rows (r = xi*5 + yj), tracking local absmax
    const float4* g4 = reinterpret_cast<const float4*>(grid);
    float mm = 0.0f;
    for (int i = tid; i < 10 * 256; i += 256) {
        int r = i >> 8, c = i & 255;
        int xi = r / 5, yj = r - xi * 5;
        int gx_ = min(x + xi, NV - 1);
        int gy_ = min(y0 + yj, NV - 1);
        float4 v = g4[(size_t)(gx_ * NV + gy_) * 256 + c];
        lds4[r * ROWSTRIDE + c] = v;
        mm = fmaxf(mm, fmaxf(fmaxf(fabsf(v.x), fabsf(v.y)),
                             fmaxf(fabsf(v.z), fabsf(v.w))));
    }

    // Block-reduce local absmax
    for (int off = 32; off > 0; off >>= 1)
        mm = fmaxf(mm, __shfl_down(mm, off));
    int lane = tid & 63, wv = tid >> 6;
    if (lane == 0) wm[wv] = mm;
    __syncthreads();                                 // covers lds4 + wm
    float amax = fmaxf(fmaxf(fmaxf(wm[0], wm[1]), fmaxf(wm[2], wm[3])), 1e-30f);

    // fp16 scale, rounded UP: guarantees amax_r >= amax, so no clamp needed.
    __half hs = __float2half_rn(amax);
    float amax_r = __half2float(hs);
    if (amax_r < amax) {                             // rn rounded down -> bump
        hs = __ushort_as_half((unsigned short)(__half_as_ushort(hs) + 1));
        amax_r = __half2float(hs);
    }
    if (tid == 0) Sc[blockIdx.x] = hs;
    float inv = 127.0f / amax_r;

    // Emit: 4 y * 128 z * 4 words = 2048 uint4 words, coalesced
    for (int i = tid; i < 2048; i += 256) {
        int L = i >> 2, w = i & 3;                   // entry-in-band, word
        int z = L & 127, yy = L >> 7;                // yy in 0..3
        int xr = w >> 1, yr = w & 1;
        int row = xr * 5 + yy + yr;
        int z1 = min(z + 1, NV - 1);
        float4 a0 = lds4[row * ROWSTRIDE + z * 2];
        float4 a1 = lds4[row * ROWSTRIDE + z * 2 + 1];
        float4 b0 = lds4[row * ROWSTRIDE + z1 * 2];
        float4 b1 = lds4[row * ROWSTRIDE + z1 * 2 + 1];
        uint4 word;
        word.x = pack4(a0, inv);
        word.y = pack4(a1, inv);
        word.z = pack4(b0, inv);
        word.w = pack4(b1, inv);
        size_t e = (size_t)((x * NV) + y0 + yy) * NV + z;
        tbl[e * 4 + w] = word;
    }
}

// ---------------------------------------------------------------------------
// Main gather: 2 queries/thread, one 64-B aligned entry per query.
// Scales staged into LDS; ipos loads and output stores are NONTEMPORAL so
// the streaming traffic doesn't evict table lines from L2.
// ---------------------------------------------------------------------------
__device__ __forceinline__ float4 dec4(uint32 w) {
    return make_float4((float)((int)(w << 24) >> 24),
                       (float)((int)(w << 16) >> 24),
                       (float)((int)(w <<  8) >> 24),
                       (float)((int)  w       >> 24));
}

__device__ __forceinline__ void acc4(float4& a, float4 v, float w) {
    a.x = fmaf(v.x, w, a.x);
    a.y = fmaf(v.y, w, a.y);
    a.z = fmaf(v.z, w, a.z);
    a.w = fmaf(v.w, w, a.w);
}

__device__ __forceinline__ void cell_of(const float* pf, int slot, size_t& e,
                                        int& sidx, float& fx, float& fy, float& fz) {
    float px = pf[slot * 3 + 0];
    float py = pf[slot * 3 + 1];
    float pz = pf[slot * 3 + 2];
    px = fminf(fmaxf(px, 0.0f), 1.0f) * (float)(NV - 1);
    py = fminf(fmaxf(py, 0.0f), 1.0f) * (float)(NV - 1);
    pz = fminf(fmaxf(pz, 0.0f), 1.0f) * (float)(NV - 1);
    int x0 = min((int)px, NV - 2);
    int y0 = min((int)py, NV - 2);
    int z0 = min((int)pz, NV - 2);
    fx = px - (float)x0;
    fy = py - (float)y0;
    fz = pz - (float)z0;
    e = (size_t)((x0 * NV + y0) * NV + z0) * 4;
    sidx = (x0 << 5) | (y0 >> 2);
}

__device__ __forceinline__ void lerp_store(const uint4* E, float fx, float fy,
                                           float fz, float s, fx4* o4, int q) {
    float gx = 1.0f - fx, gy = 1.0f - fy, gz = 1.0f - fz;
    float w0 = gx * gy, w1 = gx * fy, w2 = fx * gy, w3 = fx * fy;
    float4 a03 = make_float4(0.f, 0.f, 0.f, 0.f);
    float4 a47 = make_float4(0.f, 0.f, 0.f, 0.f);
    {
        float wg = w0 * gz, wf = w0 * fz;
        acc4(a03, dec4(E[0].x), wg); acc4(a47, dec4(E[0].y), wg);
        acc4(a03, dec4(E[0].z), wf); acc4(a47, dec4(E[0].w), wf);
    }
    {
        float wg = w1 * gz, wf = w1 * fz;
        acc4(a03, dec4(E[1].x), wg); acc4(a47, dec4(E[1].y), wg);
        acc4(a03, dec4(E[1].z), wf); acc4(a47, dec4(E[1].w), wf);
    }
    {
        float wg = w2 * gz, wf = w2 * fz;
        acc4(a03, dec4(E[2].x), wg); acc4(a47, dec4(E[2].y), wg);
        acc4(a03, dec4(E[2].z), wf); acc4(a47, dec4(E[2].w), wf);
    }
    {
        float wg = w3 * gz, wf = w3 * fz;
        acc4(a03, dec4(E[3].x), wg); acc4(a47, dec4(E[3].y), wg);
        acc4(a03, dec4(E[3].z), wf); acc4(a47, dec4(E[3].w), wf);
    }
    fx4 r0 = {a03.x * s, a03.y * s, a03.z * s, a03.w * s};
    fx4 r1 = {a47.x * s, a47.y * s, a47.z * s, a47.w * s};
    __builtin_nontemporal_store(r0, o4 + q * 2 + 0);
    __builtin_nontemporal_store(r1, o4 + q * 2 + 1);
}

__global__ __launch_bounds__(256) void trilerp_full_kernel(
        const float* __restrict__ ipos, const uint4* __restrict__ tbl,
        const __half* __restrict__ Sc, float* __restrict__ out, int nq) {
    __shared__ fx4 pls[384];                         // 512 queries x 12 B
    __shared__ __half scl[4096];                     // 8 KB scale cache
    int tid = threadIdx.x;
    int blk = blockIdx.x;

    // Stage scales: 4096 halves = 512 uint4, 2 coalesced iterations
    {
        const uint4* sc4 = reinterpret_cast<const uint4*>(Sc);
        uint4* sl4 = reinterpret_cast<uint4*>(scl);
        sl4[tid] = sc4[tid];
        sl4[tid + 256] = sc4[tid + 256];
    }
    // Stage positions (nontemporal: read-once stream)
    const fx4* ip4 = reinterpret_cast<const fx4*>(ipos);
    int n4p = (int)(((long long)nq * 3) >> 2);
    int sbase = blk * 384;
    #pragma unroll
    for (int k = 0; k < 2; ++k) {
        int i = tid + k * 256;
        if (i < 384 && sbase + i < n4p)
            pls[i] = __builtin_nontemporal_load(ip4 + sbase + i);
    }
    __syncthreads();

    int q0 = blk * 512 + tid;
    int q1 = q0 + 256;
    const float* pf = reinterpret_cast<const float*>(pls);
    fx4* o4 = reinterpret_cast<fx4*>(out);

    size_t e0 = 0, e1 = 0;
    int si0 = 0, si1 = 0;
    float fx0, fy0, fz0, fx1, fy1, fz1;
    bool v0 = q0 < nq, v1 = q1 < nq;
    if (v0) cell_of(pf, tid,       e0, si0, fx0, fy0, fz0);
    if (v1) cell_of(pf, tid + 256, e1, si1, fx1, fy1, fz1);

    uint4 E0[4], E1[4];
    float s0 = 0.f, s1 = 0.f;
    if (v0) {
        E0[0] = tbl[e0]; E0[1] = tbl[e0+1]; E0[2] = tbl[e0+2]; E0[3] = tbl[e0+3];
        s0 = __half2float(scl[si0]) * (1.0f / 127.0f);
    }
    if (v1) {
        E1[0] = tbl[e1]; E1[1] = tbl[e1+1]; E1[2] = tbl[e1+2]; E1[3] = tbl[e1+3];
        s1 = __half2float(scl[si1]) * (1.0f / 127.0f);
    }

    if (v0) lerp_store(E0, fx0, fy0, fz0, s0, o4, q0);
    if (v1) lerp_store(E1, fx1, fy1, fz1, s1, o4, q1);
}

// ---------------------------------------------------------------------------
// Fallback (direct fp32 gather) if workspace can't hold the table.
// ---------------------------------------------------------------------------
__device__ __forceinline__ float4 lerp4(float4 a, float4 b, float t) {
    return make_float4(fmaf(t, b.x - a.x, a.x),
                       fmaf(t, b.y - a.y, a.y),
                       fmaf(t, b.z - a.z, a.z),
                       fmaf(t, b.w - a.w, a.w));
}

__global__ __launch_bounds__(256) void voxel_trilerp_kernel(
        const float* __restrict__ ipos,
        const float* __restrict__ grid,
        float* __restrict__ out,
        int nq) {
    const int tid = blockIdx.x * blockDim.x + threadIdx.x;
    const int stride = gridDim.x * blockDim.x;
    const float4* __restrict__ g4 = reinterpret_cast<const float4*>(grid);
    float4* __restrict__ o4 = reinterpret_cast<float4*>(out);

    const int Z4 = 2;
    const int Y4 = NV * 8 / 4;
    const int X4 = NV * NV * 8 / 4;

    for (int q = tid; q < nq; q += stride) {
        float px = ipos[q * 3 + 0];
        float py = ipos[q * 3 + 1];
        float pz = ipos[q * 3 + 2];

        px = fminf(fmaxf(px, 0.0f), 1.0f) * (float)(NV - 1);
        py = fminf(fmaxf(py, 0.0f), 1.0f) * (float)(NV - 1);
        pz = fminf(fmaxf(pz, 0.0f), 1.0f) * (float)(NV - 1);

        int x0 = min((int)px, NV - 2);
        int y0 = min((int)py, NV - 2);
        int z0 = min((int)pz, NV - 2);

        float fx = px - (float)x0;
        float fy = py - (float)y0;
        float fz = pz - (float)z0;

        int b = x0 * X4 + y0 * Y4 + z0 * Z4;

        float4 c00a0 = g4[b],                c00a1 = g4[b + 1];
        float4 c00b0 = g4[b + Z4],           c00b1 = g4[b + Z4 + 1];
        float4 c01a0 = g4[b + Y4],           c01a1 = g4[b + Y4 + 1];
        float4 c01b0 = g4[b + Y4 + Z4],      c01b1 = g4[b + Y4 + Z4 + 1];
        float4 c10a0 = g4[b + X4],           c10a1 = g4[b + X4 + 1];
        float4 c10b0 = g4[b + X4 + Z4],      c10b1 = g4[b + X4 + Z4 + 1];
        float4 c11a0 = g4[b + X4 + Y4],      c11a1 = g4[b + X4 + Y4 + 1];
        float4 c11b0 = g4[b + X4 + Y4 + Z4], c11b1 = g4[b + X4 + Y4 + Z4 + 1];

        float4 z00_0 = lerp4(c00a0, c00b0, fz), z00_1 = lerp4(c00a1, c00b1, fz);
        float4 z01_0 = lerp4(c01a0, c01b0, fz), z01_1 = lerp4(c01a1, c01b1, fz);
        float4 z10_0 = lerp4(c10a0, c10b0, fz), z10_1 = lerp4(c10a1, c10b1, fz);
        float4 z11_0 = lerp4(c11a0, c11b0, fz), z11_1 = lerp4(c11a1, c11b1, fz);

        float4 y0_0 = lerp4(z00_0, z01_0, fy), y0_1 = lerp4(z00_1, z01_1, fy);
        float4 y1_0 = lerp4(z10_0, z11_0, fy), y1_1 = lerp4(z10_1, z11_1, fy);

        float4 r0 = lerp4(y0_0, y1_0, fx);
        float4 r1 = lerp4(y0_1, y1_1, fx);

        o4[q * 2 + 0] = r0;
        o4[q * 2 + 1] = r1;
    }
}

extern "C" void kernel_launch(void* const* d_in, const int* in_sizes, int n_in,
                              void* d_out, int out_size, void* d_ws, size_t ws_size,
                              hipStream_t stream) {
    const float* ipos = (const float*)d_in[0];
    const float* grid = (const float*)d_in[1];
    float* out = (float*)d_out;

    const int nq = in_sizes[0] / 3;           // 4194304

    if (ws_size >= TBL_BYTES) {
        uint4* tbl = (uint4*)d_ws;
        __half* Sc = (__half*)((char*)d_ws + TBL_BYTES - 32768);  // 4064 fp16 scales

        repack_full_kernel<<<127 * 32, 256, 0, stream>>>(grid, Sc, tbl);
        trilerp_full_kernel<<<(nq + 511) / 512, 256, 0, stream>>>(
            ipos, tbl, Sc, out, nq);
    } else {
        voxel_trilerp_kernel<<<2048, 256, 0, stream>>>(ipos, grid, out, nq);
    }
}